// Round 12
// baseline (129.241 us; speedup 1.0000x reference)
//
#include <hip/hip_runtime.h>

// MessagePassing: out = segment_sum(x[col], row, N)
// x: [N=100000, 32] fp32; edge_index: [2, E=1600000] int32 (row; col)
//
// PMC lessons:
//  - r4: scattered 4B global stores cost a full 64B line request each. Sort
//    first, write lane-consecutive runs.
//  - r8: LDS fp32 atomicAdd ~16cyc/op serialized. Int LDS atomics fine.
//    Accumulate in REGISTERS.
//  - r9/r11: 444->136->122.5us. Top-5 = harness d_ws poison fill (256MiB,
//    43us) + d_out fill (2us), INSIDE the timed window -> fixed ~45-50us
//    floor. Controllable ~72us = sortwrite(~30, only 196 blocks = 0.77/CU!)
//    + accum(~40, double store read + 2-way MLP).
//
// This round: CHUNK 8192->4096 (391 blocks, 2x parallelism for sortwrite);
// accum stages store in LDS once (uint4), 4-way unrolled gather.
//
// Pipeline (3 dispatches):
//   0. memset bcur[NB] = 0  (3KB)
//   1. k_sortwrite: per-chunk LDS counting sort by bucket (128 rows) +
//      slack-reserved coalesced run writes of packed (lrow<<17|col).
//      Bucket b owns store[b*SLACK ..). Binomial(1.6M,1/782): mean 2046,
//      sd 45 -> SLACK=3072 is ~22 sigma, cannot overflow.
//   2. k_accum: stage bucket entries to LDS, in-LDS counting sort by ROW
//      (int atomics, 2/edge), register accumulation over contiguous runs
//      (zero atomics, 4-way MLP), coalesced float4 output.
// Fallback to direct atomic scatter if constraints not met.

#define FEAT    32
#define QUADS   8
#define RB      128         // rows per bucket
#define RB_BITS 7
#define COLBITS 17          // pack: [lrow:7 | col:17], needs N <= 131072
#define CHUNK   4096        // edges per sortwrite block (391 blocks)
#define NBMAX   1024        // max buckets (782 actual)
#define SLACK   3072        // store slots per bucket
#define CMAX    4096        // in-bucket staging size (>= SLACK -> single pass)

static_assert(SLACK <= CMAX, "single-pass accum requires SLACK <= CMAX");

// ---------------- fallback: atomic scatter ----------------
__global__ __launch_bounds__(256) void mp_scatter_add(
    const float* __restrict__ x, const int* __restrict__ row,
    const int* __restrict__ col, float* __restrict__ out, int E)
{
    int tid = blockIdx.x * blockDim.x + threadIdx.x;
    int e = tid >> 3, q = tid & 7;
    if (e >= E) return;
    int r = row[e], c = col[e];
    float4 v = reinterpret_cast<const float4*>(x)[(size_t)c * QUADS + q];
    float* o = out + (size_t)r * FEAT + q * 4;
    atomicAdd(o + 0, v.x); atomicAdd(o + 1, v.y);
    atomicAdd(o + 2, v.z); atomicAdd(o + 3, v.w);
}

// ---------------- 1: LDS counting sort + slack-reserved run writes ----------
__global__ __launch_bounds__(512) void k_sortwrite(
    const int* __restrict__ row, const int* __restrict__ col,
    int* __restrict__ bcur, unsigned* __restrict__ store, int E, int NB)
{
    __shared__ unsigned srt[CHUNK];   // 16 KB: packed entries, bucket-sorted
    __shared__ int      dst[CHUNK];   // 16 KB: global dest per sorted position
    __shared__ int      hist[NBMAX];  // 4 KB: count -> scanned base -> cursor
    __shared__ int      rbase[NBMAX]; // 4 KB: global_base - scanned_base
    __shared__ int      pre[512];     // 2 KB

    int t = threadIdx.x;
    int base = blockIdx.x * CHUNK;
    int cc = min(CHUNK, E - base);

    for (int k = t; k < NB; k += 512) hist[k] = 0;
    __syncthreads();

    // pass 1: count buckets in this chunk
    for (int i = t; i < cc; i += 512)
        atomicAdd(&hist[row[base + i] >> RB_BITS], 1);
    __syncthreads();

    // per-thread serial exclusive over its 2 buckets + global slack reserve
    int k0 = t * 2;                 // NB <= 1024 -> 2 buckets/thread
    int s = 0;
    for (int j = 0; j < 2; ++j) {
        int k = k0 + j;
        if (k < NB) {
            int v = hist[k];
            hist[k] = s;            // local exclusive (pre thread-offset)
            if (v) {
                int res = atomicAdd(&bcur[k], v);      // slot within bucket
                rbase[k] = k * SLACK + res - s;
            }
            s += v;
        }
    }
    pre[t] = s;
    __syncthreads();
    for (int off = 1; off < 512; off <<= 1) {
        int u = (t >= off) ? pre[t - off] : 0;
        __syncthreads();
        pre[t] += u;
        __syncthreads();
    }
    int tb = (t == 0) ? 0 : pre[t - 1];
    for (int j = 0; j < 2; ++j) {
        int k = k0 + j;
        if (k < NB) {
            hist[k]  += tb;         // scanned base = LDS sort cursor start
            rbase[k] -= tb;         // global_base - scanned_base
        }
    }
    __syncthreads();

    // pass 2: scatter into bucket-sorted LDS order + compute global dest
    for (int i = t; i < cc; i += 512) {
        int e = base + i;
        int r = row[e], c = col[e];
        int b = r >> RB_BITS;
        int slot = atomicAdd(&hist[b], 1);
        srt[slot] = ((unsigned)(r & (RB - 1)) << COLBITS) | (unsigned)c;
        dst[slot] = rbase[b] + slot;
    }
    __syncthreads();

    // pass 3: lane-consecutive writes -> runs coalesce into full lines
    for (int i = t; i < cc; i += 512)
        store[dst[i]] = srt[i];
}

// ---------------- 2: in-bucket row sort + register accumulate ---------------
__global__ __launch_bounds__(512) void k_accum(
    const float* __restrict__ x, const int* __restrict__ bcur,
    const unsigned* __restrict__ store, float* __restrict__ out, int N)
{
    __shared__ unsigned raw[CMAX];      // 16 KB: staged bucket entries
    __shared__ unsigned sorted[CMAX];   // 16 KB: entries sorted by lrow
    __shared__ int rcnt[RB];            // counts -> scatter cursor
    __shared__ int rbase[RB + 1];       // row run offsets

    int t = threadIdx.x;
    int b = blockIdx.x;
    int start = b * SLACK;
    int cnt = min(bcur[b], SLACK);      // single pass: cnt <= SLACK <= CMAX
    int q = t & 7;                      // float4 quad within row
    int g = t >> 3;                     // group 0..63; owns rows g and g+64
    const float4* x4 = reinterpret_cast<const float4*>(x);
    const unsigned CMASK = (1u << COLBITS) - 1u;

    // stage store chunk into LDS once (vectorized; start is 16B-aligned)
    int nv = cnt >> 2;
    const uint4* st4 = reinterpret_cast<const uint4*>(store + start);
    uint4* raw4 = reinterpret_cast<uint4*>(raw);
    for (int i = t; i < nv; i += 512) raw4[i] = st4[i];
    for (int i = (nv << 2) + t; i < cnt; i += 512) raw[i] = store[start + i];
    if (t < RB) rcnt[t] = 0;
    __syncthreads();

    // histogram by local row (native int LDS atomics: 1 per edge)
    for (int i = t; i < cnt; i += 512)
        atomicAdd(&rcnt[raw[i] >> COLBITS], 1);
    __syncthreads();

    // inclusive Hillis-Steele scan over 128 counters
    for (int off = 1; off < RB; off <<= 1) {
        int v = 0;
        if (t < RB && t >= off) v = rcnt[t - off];
        __syncthreads();
        if (t < RB) rcnt[t] += v;
        __syncthreads();
    }
    if (t < RB) rbase[t + 1] = rcnt[t];
    if (t == 0) rbase[0] = 0;
    __syncthreads();
    if (t < RB) rcnt[t] = rbase[t];     // reuse as scatter cursor
    __syncthreads();

    // scatter into row-sorted order (int LDS atomics: 1 per edge)
    for (int i = t; i < cnt; i += 512) {
        unsigned e = raw[i];
        int slot = atomicAdd(&rcnt[e >> COLBITS], 1);
        sorted[slot] = e;
    }
    __syncthreads();

    // register accumulation over this group's two rows (NO atomics, 4-way MLP)
    float4 acc0 = make_float4(0.f, 0.f, 0.f, 0.f);
    float4 acc1 = make_float4(0.f, 0.f, 0.f, 0.f);
    for (int rr = 0; rr < 2; ++rr) {
        int r = g + rr * 64;
        int j = rbase[r], je = rbase[r + 1];
        float4 u0 = make_float4(0.f, 0.f, 0.f, 0.f);
        float4 u1 = make_float4(0.f, 0.f, 0.f, 0.f);
        float4 u2 = make_float4(0.f, 0.f, 0.f, 0.f);
        float4 u3 = make_float4(0.f, 0.f, 0.f, 0.f);
        for (; j + 4 <= je; j += 4) {
            unsigned cA = sorted[j] & CMASK;
            unsigned cB = sorted[j + 1] & CMASK;
            unsigned cC = sorted[j + 2] & CMASK;
            unsigned cD = sorted[j + 3] & CMASK;
            float4 vA = x4[(size_t)cA * QUADS + q];
            float4 vB = x4[(size_t)cB * QUADS + q];
            float4 vC = x4[(size_t)cC * QUADS + q];
            float4 vD = x4[(size_t)cD * QUADS + q];
            u0.x += vA.x; u0.y += vA.y; u0.z += vA.z; u0.w += vA.w;
            u1.x += vB.x; u1.y += vB.y; u1.z += vB.z; u1.w += vB.w;
            u2.x += vC.x; u2.y += vC.y; u2.z += vC.z; u2.w += vC.w;
            u3.x += vD.x; u3.y += vD.y; u3.z += vD.z; u3.w += vD.w;
        }
        for (; j < je; ++j) {
            unsigned cA = sorted[j] & CMASK;
            float4 vA = x4[(size_t)cA * QUADS + q];
            u0.x += vA.x; u0.y += vA.y; u0.z += vA.z; u0.w += vA.w;
        }
        float4& acc = rr ? acc1 : acc0;
        acc.x += (u0.x + u1.x) + (u2.x + u3.x);
        acc.y += (u0.y + u1.y) + (u2.y + u3.y);
        acc.z += (u0.z + u1.z) + (u2.z + u3.z);
        acc.w += (u0.w + u1.w) + (u2.w + u3.w);
    }

    // coalesced writes: wave covers 8 consecutive rows (1 KB) per round
    int row0 = b * RB;
    float4* out4 = reinterpret_cast<float4*>(out);
    int r0 = row0 + g;
    if (r0 < N) out4[(size_t)r0 * QUADS + q] = acc0;
    int r1 = row0 + 64 + g;
    if (r1 < N) out4[(size_t)r1 * QUADS + q] = acc1;
}

extern "C" void kernel_launch(void* const* d_in, const int* in_sizes, int n_in,
                              void* d_out, int out_size, void* d_ws, size_t ws_size,
                              hipStream_t stream) {
    const float* x   = (const float*)d_in[0];
    const int*   ei  = (const int*)d_in[1];
    float*       out = (float*)d_out;

    const int E = in_sizes[1] / 2;           // edge_index is [2, E]
    const int N = in_sizes[0] / FEAT;        // 100000
    const int* row = ei;
    const int* col = ei + E;

    const int NB = (N + RB - 1) >> RB_BITS;  // 782

    // ws layout (ints): bcur[NBMAX] | store[NB*SLACK]
    int*      bcur  = (int*)d_ws;
    unsigned* store = (unsigned*)(bcur + NBMAX);
    size_t need = ((size_t)NBMAX + (size_t)NB * SLACK) * sizeof(int);

    if (ws_size >= need && N <= (1 << COLBITS) && NB <= NBMAX) {
        hipMemsetAsync(bcur, 0, (size_t)NB * sizeof(int), stream);
        const int GP = (E + CHUNK - 1) / CHUNK;        // 391
        k_sortwrite<<<GP, 512, 0, stream>>>(row, col, bcur, store, E, NB);
        k_accum    <<<NB, 512, 0, stream>>>(x, bcur, store, out, N);
    } else {
        hipMemsetAsync(d_out, 0, (size_t)out_size * sizeof(float), stream);
        const int total = E * QUADS;
        mp_scatter_add<<<(total + 255) / 256, 256, 0, stream>>>(x, row, col, out, E);
    }
}

// Round 14
// 122.540 us; speedup vs baseline: 1.0547x; 1.0547x over previous
//
#include <hip/hip_runtime.h>

// MessagePassing: out = segment_sum(x[col], row, N)
// x: [N=100000, 32] fp32; edge_index: [2, E=1600000] int32 (row; col)
//
// PMC lessons:
//  - r4: scattered 4B global stores cost a full 64B line request each. Sort
//    first, write lane-consecutive runs.
//  - r8: LDS fp32 atomicAdd ~16cyc/op serialized. Int LDS atomics fine.
//    Accumulate in REGISTERS.
//  - r9/r11: 444->136->122.5us. Top-5 = harness d_ws poison fill (256MiB,
//    43us each) INSIDE timed window -> fixed ~45-50us floor.
//  - r12: CHUNK 8192->4096 REGRESSED (+6.7us): 391 blocks on 256 CUs pays
//    per-block fixed cost (hist zero + 18-barrier scan + reserve atomics)
//    2x with near-worst grid imbalance (1.53/CU). Keep CHUNK=8192 (196
//    blocks, <=1/CU).
//
// Pipeline (3 dispatches):
//   0. memset bcur[NB] = 0  (3KB)
//   1. k_sortwrite (CHUNK=8192): per-chunk LDS counting sort by bucket +
//      slack-reserved coalesced run writes of packed (lrow<<17|col).
//      Bucket b owns store[b*SLACK ..). Binomial(1.6M,1/782): mean 2046,
//      sd 45 -> SLACK=3072 is ~22 sigma, cannot overflow.
//   2. k_accum: stage bucket entries to LDS once (uint4), in-LDS counting
//      sort by ROW (int atomics, 2/edge), register accumulation over
//      contiguous runs (zero atomics, 4-way MLP), coalesced float4 output.
// Fallback to direct atomic scatter if constraints not met.

#define FEAT    32
#define QUADS   8
#define RB      128         // rows per bucket
#define RB_BITS 7
#define COLBITS 17          // pack: [lrow:7 | col:17], needs N <= 131072
#define CHUNK   8192        // edges per sortwrite block (196 blocks)
#define NBMAX   1024        // max buckets (782 actual)
#define SLACK   3072        // store slots per bucket
#define CMAX    4096        // in-bucket staging size (>= SLACK -> single pass)

static_assert(SLACK <= CMAX, "single-pass accum requires SLACK <= CMAX");

// ---------------- fallback: atomic scatter ----------------
__global__ __launch_bounds__(256) void mp_scatter_add(
    const float* __restrict__ x, const int* __restrict__ row,
    const int* __restrict__ col, float* __restrict__ out, int E)
{
    int tid = blockIdx.x * blockDim.x + threadIdx.x;
    int e = tid >> 3, q = tid & 7;
    if (e >= E) return;
    int r = row[e], c = col[e];
    float4 v = reinterpret_cast<const float4*>(x)[(size_t)c * QUADS + q];
    float* o = out + (size_t)r * FEAT + q * 4;
    atomicAdd(o + 0, v.x); atomicAdd(o + 1, v.y);
    atomicAdd(o + 2, v.z); atomicAdd(o + 3, v.w);
}

// ---------------- 1: LDS counting sort + slack-reserved run writes ----------
__global__ __launch_bounds__(512) void k_sortwrite(
    const int* __restrict__ row, const int* __restrict__ col,
    int* __restrict__ bcur, unsigned* __restrict__ store, int E, int NB)
{
    __shared__ unsigned srt[CHUNK];   // 32 KB: packed entries, bucket-sorted
    __shared__ int      dst[CHUNK];   // 32 KB: global dest per sorted position
    __shared__ int      hist[NBMAX];  // 4 KB: count -> scanned base -> cursor
    __shared__ int      rbase[NBMAX]; // 4 KB: global_base - scanned_base
    __shared__ int      pre[512];     // 2 KB

    int t = threadIdx.x;
    int base = blockIdx.x * CHUNK;
    int cc = min(CHUNK, E - base);

    for (int k = t; k < NB; k += 512) hist[k] = 0;
    __syncthreads();

    // pass 1: count buckets in this chunk
    for (int i = t; i < cc; i += 512)
        atomicAdd(&hist[row[base + i] >> RB_BITS], 1);
    __syncthreads();

    // per-thread serial exclusive over its 2 buckets + global slack reserve
    int k0 = t * 2;                 // NB <= 1024 -> 2 buckets/thread
    int s = 0;
    for (int j = 0; j < 2; ++j) {
        int k = k0 + j;
        if (k < NB) {
            int v = hist[k];
            hist[k] = s;            // local exclusive (pre thread-offset)
            if (v) {
                int res = atomicAdd(&bcur[k], v);      // slot within bucket
                rbase[k] = k * SLACK + res - s;
            }
            s += v;
        }
    }
    pre[t] = s;
    __syncthreads();
    for (int off = 1; off < 512; off <<= 1) {
        int u = (t >= off) ? pre[t - off] : 0;
        __syncthreads();
        pre[t] += u;
        __syncthreads();
    }
    int tb = (t == 0) ? 0 : pre[t - 1];
    for (int j = 0; j < 2; ++j) {
        int k = k0 + j;
        if (k < NB) {
            hist[k]  += tb;         // scanned base = LDS sort cursor start
            rbase[k] -= tb;         // global_base - scanned_base
        }
    }
    __syncthreads();

    // pass 2: scatter into bucket-sorted LDS order + compute global dest
    for (int i = t; i < cc; i += 512) {
        int e = base + i;
        int r = row[e], c = col[e];
        int b = r >> RB_BITS;
        int slot = atomicAdd(&hist[b], 1);
        srt[slot] = ((unsigned)(r & (RB - 1)) << COLBITS) | (unsigned)c;
        dst[slot] = rbase[b] + slot;
    }
    __syncthreads();

    // pass 3: lane-consecutive writes -> runs coalesce into full lines
    for (int i = t; i < cc; i += 512)
        store[dst[i]] = srt[i];
}

// ---------------- 2: in-bucket row sort + register accumulate ---------------
__global__ __launch_bounds__(512) void k_accum(
    const float* __restrict__ x, const int* __restrict__ bcur,
    const unsigned* __restrict__ store, float* __restrict__ out, int N)
{
    __shared__ unsigned raw[CMAX];      // 16 KB: staged bucket entries
    __shared__ unsigned sorted[CMAX];   // 16 KB: entries sorted by lrow
    __shared__ int rcnt[RB];            // counts -> scatter cursor
    __shared__ int rbase[RB + 1];       // row run offsets

    int t = threadIdx.x;
    int b = blockIdx.x;
    int start = b * SLACK;
    int cnt = min(bcur[b], SLACK);      // single pass: cnt <= SLACK <= CMAX
    int q = t & 7;                      // float4 quad within row
    int g = t >> 3;                     // group 0..63; owns rows g and g+64
    const float4* x4 = reinterpret_cast<const float4*>(x);
    const unsigned CMASK = (1u << COLBITS) - 1u;

    // stage store chunk into LDS once (vectorized; start is 16B-aligned)
    int nv = cnt >> 2;
    const uint4* st4 = reinterpret_cast<const uint4*>(store + start);
    uint4* raw4 = reinterpret_cast<uint4*>(raw);
    for (int i = t; i < nv; i += 512) raw4[i] = st4[i];
    for (int i = (nv << 2) + t; i < cnt; i += 512) raw[i] = store[start + i];
    if (t < RB) rcnt[t] = 0;
    __syncthreads();

    // histogram by local row (native int LDS atomics: 1 per edge)
    for (int i = t; i < cnt; i += 512)
        atomicAdd(&rcnt[raw[i] >> COLBITS], 1);
    __syncthreads();

    // inclusive Hillis-Steele scan over 128 counters
    for (int off = 1; off < RB; off <<= 1) {
        int v = 0;
        if (t < RB && t >= off) v = rcnt[t - off];
        __syncthreads();
        if (t < RB) rcnt[t] += v;
        __syncthreads();
    }
    if (t < RB) rbase[t + 1] = rcnt[t];
    if (t == 0) rbase[0] = 0;
    __syncthreads();
    if (t < RB) rcnt[t] = rbase[t];     // reuse as scatter cursor
    __syncthreads();

    // scatter into row-sorted order (int LDS atomics: 1 per edge)
    for (int i = t; i < cnt; i += 512) {
        unsigned e = raw[i];
        int slot = atomicAdd(&rcnt[e >> COLBITS], 1);
        sorted[slot] = e;
    }
    __syncthreads();

    // register accumulation over this group's two rows (NO atomics, 4-way MLP)
    float4 acc0 = make_float4(0.f, 0.f, 0.f, 0.f);
    float4 acc1 = make_float4(0.f, 0.f, 0.f, 0.f);
    for (int rr = 0; rr < 2; ++rr) {
        int r = g + rr * 64;
        int j = rbase[r], je = rbase[r + 1];
        float4 u0 = make_float4(0.f, 0.f, 0.f, 0.f);
        float4 u1 = make_float4(0.f, 0.f, 0.f, 0.f);
        float4 u2 = make_float4(0.f, 0.f, 0.f, 0.f);
        float4 u3 = make_float4(0.f, 0.f, 0.f, 0.f);
        for (; j + 4 <= je; j += 4) {
            unsigned cA = sorted[j] & CMASK;
            unsigned cB = sorted[j + 1] & CMASK;
            unsigned cC = sorted[j + 2] & CMASK;
            unsigned cD = sorted[j + 3] & CMASK;
            float4 vA = x4[(size_t)cA * QUADS + q];
            float4 vB = x4[(size_t)cB * QUADS + q];
            float4 vC = x4[(size_t)cC * QUADS + q];
            float4 vD = x4[(size_t)cD * QUADS + q];
            u0.x += vA.x; u0.y += vA.y; u0.z += vA.z; u0.w += vA.w;
            u1.x += vB.x; u1.y += vB.y; u1.z += vB.z; u1.w += vB.w;
            u2.x += vC.x; u2.y += vC.y; u2.z += vC.z; u2.w += vC.w;
            u3.x += vD.x; u3.y += vD.y; u3.z += vD.z; u3.w += vD.w;
        }
        for (; j < je; ++j) {
            unsigned cA = sorted[j] & CMASK;
            float4 vA = x4[(size_t)cA * QUADS + q];
            u0.x += vA.x; u0.y += vA.y; u0.z += vA.z; u0.w += vA.w;
        }
        float4& acc = rr ? acc1 : acc0;
        acc.x += (u0.x + u1.x) + (u2.x + u3.x);
        acc.y += (u0.y + u1.y) + (u2.y + u3.y);
        acc.z += (u0.z + u1.z) + (u2.z + u3.z);
        acc.w += (u0.w + u1.w) + (u2.w + u3.w);
    }

    // coalesced writes: wave covers 8 consecutive rows (1 KB) per round
    int row0 = b * RB;
    float4* out4 = reinterpret_cast<float4*>(out);
    int r0 = row0 + g;
    if (r0 < N) out4[(size_t)r0 * QUADS + q] = acc0;
    int r1 = row0 + 64 + g;
    if (r1 < N) out4[(size_t)r1 * QUADS + q] = acc1;
}

extern "C" void kernel_launch(void* const* d_in, const int* in_sizes, int n_in,
                              void* d_out, int out_size, void* d_ws, size_t ws_size,
                              hipStream_t stream) {
    const float* x   = (const float*)d_in[0];
    const int*   ei  = (const int*)d_in[1];
    float*       out = (float*)d_out;

    const int E = in_sizes[1] / 2;           // edge_index is [2, E]
    const int N = in_sizes[0] / FEAT;        // 100000
    const int* row = ei;
    const int* col = ei + E;

    const int NB = (N + RB - 1) >> RB_BITS;  // 782

    // ws layout (ints): bcur[NBMAX] | store[NB*SLACK]
    int*      bcur  = (int*)d_ws;
    unsigned* store = (unsigned*)(bcur + NBMAX);
    size_t need = ((size_t)NBMAX + (size_t)NB * SLACK) * sizeof(int);

    if (ws_size >= need && N <= (1 << COLBITS) && NB <= NBMAX) {
        hipMemsetAsync(bcur, 0, (size_t)NB * sizeof(int), stream);
        const int GP = (E + CHUNK - 1) / CHUNK;        // 196
        k_sortwrite<<<GP, 512, 0, stream>>>(row, col, bcur, store, E, NB);
        k_accum    <<<NB, 512, 0, stream>>>(x, bcur, store, out, N);
    } else {
        hipMemsetAsync(d_out, 0, (size_t)out_size * sizeof(float), stream);
        const int total = E * QUADS;
        mp_scatter_add<<<(total + 255) / 256, 256, 0, stream>>>(x, row, col, out, E);
    }
}